// Round 1
// baseline (1592.430 us; speedup 1.0000x reference)
//
#include <hip/hip_runtime.h>

// Path signature, depth 5, d=10, L=128, B=256.
// One 512-thread block per batch. Levels 1-4 state in LDS; level-5
// accumulator distributed across registers (20 j-indices x 10 channels
// per thread). Horner/Chen update per segment, 4 barriers per segment.

#define D       10
#define LPATH   128
#define NSEG    127          // L-1 segments
#define BLOCK   512
#define NJ      20           // ceil(10000 / 512)
#define N2      100
#define N3      1000
#define N4      10000
#define OUT_PER_B 111110     // 10+100+1000+10000+100000

__global__ __launch_bounds__(BLOCK) void sig_kernel(
        const float* __restrict__ path,   // [B][D][LPATH]
        float* __restrict__ out)          // [B][OUT_PER_B]
{
    __shared__ float S1[D];
    __shared__ float S2[N2];
    __shared__ float S3[N3];
    __shared__ float S4[N4];
    __shared__ float v[4][D];     // u1 chains for targets 5,4,3,2
    __shared__ float y[3][N2];    // u2 chains for targets 5,4,3
    __shared__ float w[2][N3];    // u3 chains for targets 5,4
    __shared__ float dAll[NSEG * D];

    const int tid = threadIdx.x;
    const int b   = blockIdx.x;
    const float* pb = path + (size_t)b * (D * LPATH);

    // ---- init state to zero, precompute all segment increments ----
    for (int idx = tid; idx < N4; idx += BLOCK) S4[idx] = 0.f;
    for (int idx = tid; idx < N3; idx += BLOCK) S3[idx] = 0.f;
    for (int idx = tid; idx < N2 + D; idx += BLOCK) {
        if (idx < D) S1[idx] = 0.f; else S2[idx - D] = 0.f;
    }
    for (int idx = tid; idx < NSEG * D; idx += BLOCK) {
        int c = idx / NSEG;
        int t = idx - c * NSEG;
        dAll[t * D + c] = pb[c * LPATH + t + 1] - pb[c * LPATH + t];
    }

    float acc[NJ][D];   // level-5 accumulator, j = tid + 512*i
#pragma unroll
    for (int i = 0; i < NJ; i++)
#pragma unroll
        for (int e = 0; e < D; e++) acc[i][e] = 0.f;

    __syncthreads();

    for (int t = 0; t < NSEG; t++) {
        const float* dt = &dAll[t * D];
        float dreg[D];              // statically-indexed copy for FMA loop
#pragma unroll
        for (int e = 0; e < D; e++) dreg[e] = dt[e];

        // ---- P1: u1 chains  v[k] = S1 + delta/k  (k=5,4,3,2) ----
        if (tid < 4 * D) {
            int kk = tid / D;            // 0->T5, 1->T4, 2->T3, 3->T2
            int c  = tid - kk * D;
            float inv = (kk == 0) ? 0.2f : (kk == 1) ? 0.25f
                       : (kk == 2) ? (1.f / 3.f) : 0.5f;
            v[kk][c] = S1[c] + dt[c] * inv;
        }
        __syncthreads();

        // ---- P2: u2 chains  y[k] = S2 + v[k] (x) delta / (k-1); S1 += d ----
        if (tid < 310) {
            if (tid < 300) {
                int kk  = tid / N2;          // 0->/4, 1->/3, 2->/2
                int rem = tid - kk * N2;
                int c1  = rem / D;
                int c2  = rem - c1 * D;
                float inv = (kk == 0) ? 0.25f : (kk == 1) ? (1.f / 3.f) : 0.5f;
                y[kk][rem] = S2[rem] + v[kk][c1] * dt[c2] * inv;
            } else {
                int c = tid - 300;
                S1[c] = S1[c] + dt[c];
            }
        }
        __syncthreads();

        // ---- P3: u3 chains  w[k] = S3 + y[k] (x) delta / (k-2); S2 update ----
        for (int idx = tid; idx < 2100; idx += BLOCK) {
            if (idx < 2000) {
                int kk  = idx / N3;          // 0->/3, 1->/2
                int rem = idx - kk * N3;
                int m2  = rem / D;
                int c3  = rem - m2 * D;
                float inv = (kk == 0) ? (1.f / 3.f) : 0.5f;
                w[kk][rem] = S3[rem] + y[kk][m2] * dt[c3] * inv;
            } else {
                int m  = idx - 2000;
                int c1 = m / D;
                int c2 = m - c1 * D;
                S2[m] += v[3][c1] * dt[c2];
            }
        }
        __syncthreads();

        // ---- P4: S3 update; fused C4 compute + S4 update + S5 accumulate ----
        for (int idx = tid; idx < N3; idx += BLOCK) {
            int m2 = idx / D;
            int c3 = idx - m2 * D;
            S3[idx] += y[2][m2] * dt[c3];
        }
#pragma unroll
        for (int i = 0; i < NJ; i++) {
            int j = tid + i * BLOCK;
            if (j < N4) {
                int m  = j / D;
                int dd = j - m * D;
                float dl = dt[dd];
                float s4 = S4[j];
                float c4 = s4 + w[0][m] * dl * 0.5f;   // u4 for target 5
                S4[j]    = s4 + w[1][m] * dl;          // new S4
#pragma unroll
                for (int e = 0; e < D; e++) acc[i][e] += c4 * dreg[e];
            }
        }
        __syncthreads();
    }

    // ---- epilogue: write levels 1..4 (coalesced), then level 5 ----
    float* ob = out + (size_t)b * OUT_PER_B;
    for (int idx = tid; idx < 1110 + N4; idx += BLOCK) {
        float val;
        if (idx < 10)        val = S1[idx];
        else if (idx < 110)  val = S2[idx - 10];
        else if (idx < 1110) val = S3[idx - 110];
        else                 val = S4[idx - 1110];
        ob[idx] = val;
    }
    float* o5 = ob + 11110;
#pragma unroll
    for (int i = 0; i < NJ; i++) {
        int j = tid + i * BLOCK;
        if (j < N4) {
#pragma unroll
            for (int e = 0; e < D; e++) o5[j * D + e] = acc[i][e];
        }
    }
}

extern "C" void kernel_launch(void* const* d_in, const int* in_sizes, int n_in,
                              void* d_out, int out_size, void* d_ws, size_t ws_size,
                              hipStream_t stream) {
    const float* path = (const float*)d_in[0];
    float* out = (float*)d_out;
    int B = in_sizes[0] / (D * LPATH);   // 256
    sig_kernel<<<B, BLOCK, 0, stream>>>(path, out);
}

// Round 2
// 740.536 us; speedup vs baseline: 2.1504x; 2.1504x over previous
//
#include <hip/hip_runtime.h>

// Path signature, depth 5, d=10, L=128, B=256.
// Grid = B x 10 blocks: block (b, g) owns the level-4/5 slices whose leading
// channel index is g (level-4: 1000 elems, level-5: 10000 elems). All blocks
// redundantly maintain S1-S3 (cheap, ~10% overhead); w-chains / S4 / S5 are
// sliced. Level-5 accumulator in registers: 4 j-indices x 10 channels = 40
// VGPRs/thread (no spill, vs 200 in R1). 3 barriers/segment (v-chain hoisted
// into previous segment's P4).

#define D       10
#define LPATH   128
#define NSEG    127
#define BLOCK   256
#define G       10          // blocks per batch = leading-channel split
#define NJ      4           // ceil(1000 / 256) local level-4 indices per thread
#define N2      100
#define N3      1000
#define OUT_PER_B 111110

__global__ __launch_bounds__(BLOCK) void sig_kernel(
        const float* __restrict__ path,   // [B][D][LPATH]
        float* __restrict__ out)          // [B][OUT_PER_B]
{
    __shared__ float S1[D];
    __shared__ float S2[N2];
    __shared__ float S3[N3];
    __shared__ float S4s[N3];        // S4 slice (c1 = g): local jl = c2*100+c3*10+c4
    __shared__ float w0[100];        // target-5 u3 chain, m3 slice (c1 = g)
    __shared__ float w1[100];        // target-4 u3 chain, m3 slice
    __shared__ float y0[D];          // target-5 u2 chain at m2 = (g, c2)
    __shared__ float y1[D];          // target-4 u2 chain at m2 = (g, c2)
    __shared__ float y2[N2];         // target-3 u2 chain, full
    __shared__ float v[4][D];        // u1 chains (t5,t4,t3,t2), full
    __shared__ float dAll[NSEG * D];

    const int tid = threadIdx.x;
    const int bb  = blockIdx.x;
    const int b   = bb / G;
    const int g   = bb - b * G;
    const float* pb = path + (size_t)b * (D * LPATH);

    // ---- init: zero state, precompute segment increments ----
    for (int idx = tid; idx < N3; idx += BLOCK) { S3[idx] = 0.f; S4s[idx] = 0.f; }
    if (tid < D + N2) { if (tid < D) S1[tid] = 0.f; else S2[tid - D] = 0.f; }
    for (int idx = tid; idx < NSEG * D; idx += BLOCK) {
        int t = idx / D;
        int c = idx - t * D;
        dAll[idx] = pb[c * LPATH + t + 1] - pb[c * LPATH + t];
    }

    float acc[NJ][D];
#pragma unroll
    for (int i = 0; i < NJ; i++)
#pragma unroll
        for (int e = 0; e < D; e++) acc[i][e] = 0.f;

    __syncthreads();

    // v for segment 0 (S1 == 0)
    if (tid < 4 * D) {
        int kk = tid / D;
        int c  = tid - kk * D;
        float inv = (kk == 0) ? 0.2f : (kk == 1) ? 0.25f
                   : (kk == 2) ? (1.f / 3.f) : 0.5f;
        v[kk][c] = dAll[c] * inv;
    }
    __syncthreads();

    for (int t = 0; t < NSEG; t++) {
        const float* dt = &dAll[t * D];
        float dreg[D];
#pragma unroll
        for (int e = 0; e < D; e++) dreg[e] = dt[e];

        // ---- P2: y chains (y0,y1 sliced, y2 full); S1 += d ----
        if (tid < 130) {
            if (tid < 100) {
                int c1 = tid / D, c2 = tid - c1 * D;
                y2[tid] = S2[tid] + v[2][c1] * dreg[c2] * 0.5f;
            } else if (tid < 110) {
                int c = tid - 100;
                y0[c] = S2[D * g + c] + v[0][g] * dreg[c] * 0.25f;
            } else if (tid < 120) {
                int c = tid - 110;
                y1[c] = S2[D * g + c] + v[1][g] * dreg[c] * (1.f / 3.f);
            } else {
                int c = tid - 120;
                S1[c] += dreg[c];
            }
        }
        __syncthreads();

        // ---- P3: w chains (sliced); S2 += v3 (x) d ----
        {
            int idx = tid;
            if (idx < 300) {
                if (idx < 100) {
                    int m2l = idx / D, c3 = idx - m2l * D;
                    w0[idx] = S3[100 * g + idx] + y0[m2l] * dreg[c3] * (1.f / 3.f);
                } else if (idx < 200) {
                    int l = idx - 100;
                    int m2l = l / D, c3 = l - m2l * D;
                    w1[l] = S3[100 * g + l] + y1[m2l] * dreg[c3] * 0.5f;
                } else {
                    int m = idx - 200;
                    int c1 = m / D, c2 = m - c1 * D;
                    S2[m] += v[3][c1] * dreg[c2];
                }
            }
            idx = tid + BLOCK;   // only 300 items total; tid<44 get a 2nd item
            if (idx < 300) {
                int m = idx - 200;
                int c1 = m / D, c2 = m - c1 * D;
                S2[m] += v[3][c1] * dreg[c2];
            }
        }
        __syncthreads();

        // ---- P4: S3 full update; S4 slice + level-5 accumulate; next v ----
#pragma unroll
        for (int i = 0; i < NJ; i++) {
            int idx = tid + i * BLOCK;
            if (idx < N3) {
                int m2 = idx / D, c3 = idx - m2 * D;
                S3[idx] += y2[m2] * dreg[c3];
            }
        }
#pragma unroll
        for (int i = 0; i < NJ; i++) {
            int jl = tid + i * BLOCK;
            if (jl < N3) {
                int m3l = jl / D, c4 = jl - m3l * D;
                float dl  = dreg[c4];
                float s4  = S4s[jl];
                float c4v = s4 + w0[m3l] * dl * 0.5f;
                S4s[jl]   = s4 + w1[m3l] * dl;
#pragma unroll
                for (int e = 0; e < D; e++) acc[i][e] += c4v * dreg[e];
            }
        }
        if (tid < 4 * D && t + 1 < NSEG) {
            int kk = tid / D;
            int c  = tid - kk * D;
            float inv = (kk == 0) ? 0.2f : (kk == 1) ? 0.25f
                       : (kk == 2) ? (1.f / 3.f) : 0.5f;
            v[kk][c] = S1[c] + dAll[(t + 1) * D + c] * inv;
        }
        __syncthreads();
    }

    // ---- epilogue ----
    float* ob = out + (size_t)b * OUT_PER_B;
    if (g == 0) {
        for (int idx = tid; idx < 1110; idx += BLOCK) {
            float val;
            if (idx < 10)       val = S1[idx];
            else if (idx < 110) val = S2[idx - 10];
            else                val = S3[idx - 110];
            ob[idx] = val;
        }
    }
    // level-4 slice
    for (int jl = tid; jl < N3; jl += BLOCK)
        ob[1110 + 1000 * g + jl] = S4s[jl];
    // level-5 slice
    float* o5 = ob + 11110 + (size_t)10000 * g;
#pragma unroll
    for (int i = 0; i < NJ; i++) {
        int jl = tid + i * BLOCK;
        if (jl < N3) {
#pragma unroll
            for (int e = 0; e < D; e++) o5[jl * D + e] = acc[i][e];
        }
    }
}

extern "C" void kernel_launch(void* const* d_in, const int* in_sizes, int n_in,
                              void* d_out, int out_size, void* d_ws, size_t ws_size,
                              hipStream_t stream) {
    const float* path = (const float*)d_in[0];
    float* out = (float*)d_out;
    int B = in_sizes[0] / (D * LPATH);   // 256
    sig_kernel<<<B * G, BLOCK, 0, stream>>>(path, out);
}

// Round 3
// 298.901 us; speedup vs baseline: 5.3276x; 2.4775x over previous
//
#include <hip/hip_runtime.h>

// Path signature depth 5, d=10, L=128, B=256 — GEMM restructure.
//
// Chen/Horner chains give, with prefix states S1..S3 (before segment t):
//   w1(t)[m3] = S3(t)[m3] + u24(t)[c2]*dt[c3]/2   (target-4 chain, div 4,3,2)
//   w0(t)[m3] = S3(t)[m3] + u25(t)[c2]*dt[c3]/3   (target-5 chain, div 5,4,3)
//   S4  = sum_t w1(t) (x) dt
//   S5  = sum_s W1[.,s] * ds[c4] * P(s)[e]  +  1/2 sum_t W0[.,t] * dt[c4]*dt[e]
// where P(s)[e] = sum_{u>s} du[e] (suffix sum). So levels 4/5 are GEMMs with
// K=127 (x2) whose B rows are outer products of small tables -> built on the
// fly in registers. Grid = (b,g): block owns leading channel c1=g slice
// (M=100). Thread (tm=tid/10, tn=tid%10), tid<250: C-tile 4 m3 x 10 e in
// registers, c4 = tn. W1/W0 produced chunk-wise (KC=32) by a 100-lane scan.

#define D10    10
#define LPATH  128
#define NSEG   127
#define BLOCK  256
#define G      10
#define KC     32
#define RS     16          // padded LDS row stride for dT/Pt (16B-aligned rows)
#define OUT_PER_B 111110

__global__ __launch_bounds__(BLOCK) void sig_kernel(
        const float* __restrict__ path,   // [B][D10][LPATH]
        float* __restrict__ out)          // [B][OUT_PER_B]
{
    __shared__ __align__(16) float dT[NSEG * RS];        // delta table
    __shared__ __align__(16) float Pt[NSEG * RS];        // suffix sums
    __shared__ float S1g[NSEG + 1];                      // prefix of delta[.,g]
    __shared__ float S2g[(NSEG + 1) * D10];              // S2 slice prefix
    __shared__ __align__(16) float Wp[2 * KC * 100];     // W1|W0 chunk panels

    const int tid = threadIdx.x;
    const int bb  = blockIdx.x;
    const int b   = bb / G;
    const int g   = bb - b * G;
    const float* pb = path + (size_t)b * (D10 * LPATH);

    const int tm = tid / 10;          // m-group (tid<250) / c2 (scan, tid<100)
    const int tn = tid - tm * 10;     // c4 = e-col group  / c3 (scan)

    // ---- setup: delta table ----
    for (int idx = tid; idx < NSEG * D10; idx += BLOCK) {
        int t = idx / D10, c = idx - t * D10;
        dT[t * RS + c] = pb[c * LPATH + t + 1] - pb[c * LPATH + t];
    }
    __syncthreads();

    // ---- S1g prefix (lanes 0..127); Pt suffix (lanes 128..137) ----
    if (tid <= NSEG) {
        float s = 0.f;
        for (int u = 0; u < tid; u++) s += dT[u * RS + g];
        S1g[tid] = s;
    } else if (tid < 128 + D10) {
        int e = tid - 128;
        float p = 0.f;
        for (int t = NSEG - 1; t >= 0; t--) { Pt[t * RS + e] = p; p += dT[t * RS + e]; }
    }
    __syncthreads();

    // ---- S2g prefix (lanes 0..9) ----
    if (tid < D10) {
        float s2 = 0.f;
        for (int t = 0; t <= NSEG; t++) {
            S2g[t * D10 + tid] = s2;
            if (t < NSEG) s2 += (S1g[t] + dT[t * RS + g] * 0.5f) * dT[t * RS + tid];
        }
    }
    __syncthreads();

    // ---- main: chunked scan (W1/W0 panels) + GEMM accumulate ----
    float acc[4][10];
    float s4a[4] = {0.f, 0.f, 0.f, 0.f};
#pragma unroll
    for (int i = 0; i < 4; i++)
#pragma unroll
        for (int e = 0; e < 10; e++) acc[i][e] = 0.f;
    float s3 = 0.f;   // S3 slice prefix, lane m3l = tid (tid<100)

    for (int kc0 = 0; kc0 < NSEG; kc0 += KC) {
        const int kn = (NSEG - kc0 < KC) ? (NSEG - kc0) : KC;

        if (tid < 100) {            // scan: c2 = tm, c3 = tn
            for (int kl = 0; kl < kn; kl++) {
                int t = kc0 + kl;
                float dg  = dT[t * RS + g];
                float dc2 = dT[t * RS + tm];
                float dc3 = dT[t * RS + tn];
                float s1  = S1g[t];
                float s2  = S2g[t * D10 + tm];
                float u24 = s2 + (s1 + dg * 0.25f)       * dc2 * (1.f / 3.f);
                float u25 = s2 + (s1 + dg * 0.2f)        * dc2 * 0.25f;
                float u23 = s2 + (s1 + dg * (1.f / 3.f)) * dc2 * 0.5f;
                Wp[kl * 100 + tid]        = s3 + u24 * dc3 * 0.5f;
                Wp[(KC + kl) * 100 + tid] = s3 + u25 * dc3 * (1.f / 3.f);
                s3 += u23 * dc3;
            }
        }
        __syncthreads();

        if (tid < 250) {
#pragma unroll 2
            for (int kl = 0; kl < kn; kl++) {
                int t = kc0 + kl;
                const float* drow = &dT[t * RS];
                const float* prow = &Pt[t * RS];
                float dn = drow[tn];
                float4 a1 = *(const float4*)&Wp[kl * 100 + tm * 4];
                float4 a0 = *(const float4*)&Wp[(KC + kl) * 100 + tm * 4];
                float4 p0 = *(const float4*)prow;
                float4 p1 = *(const float4*)(prow + 4);
                float4 d0 = *(const float4*)drow;
                float4 d1 = *(const float4*)(drow + 4);
                float pv[10] = {p0.x, p0.y, p0.z, p0.w, p1.x, p1.y, p1.z, p1.w,
                                prow[8], prow[9]};
                float dv[10] = {d0.x, d0.y, d0.z, d0.w, d1.x, d1.y, d1.z, d1.w,
                                drow[8], drow[9]};
                float A1[4] = {a1.x, a1.y, a1.z, a1.w};
                float A0[4] = {a0.x, a0.y, a0.z, a0.w};
                float s0v = dn * 0.5f;
#pragma unroll
                for (int i = 0; i < 4; i++) {
                    float x1 = A1[i] * dn;
                    float x0 = A0[i] * s0v;
                    s4a[i] += x1;
#pragma unroll
                    for (int e = 0; e < 10; e++) {
                        acc[i][e] += x1 * pv[e];
                        acc[i][e] += x0 * dv[e];
                    }
                }
            }
        }
        __syncthreads();   // protect Wp before next chunk's scan
    }

    // ---- epilogue ----
    float* ob = out + (size_t)b * OUT_PER_B;
    if (tid < 100) ob[110 + g * 100 + tid] = s3;              // level 3 slice
    if (tid < D10) ob[10 + g * 10 + tid] = S2g[NSEG * D10 + tid];  // level 2
    if (tid == 255) ob[g] = S1g[NSEG];                        // level 1 (chan g)
    if (tid < 250) {
#pragma unroll
        for (int i = 0; i < 4; i++) {
            int m3 = tm * 4 + i;
            ob[1110 + g * 1000 + m3 * 10 + tn] = s4a[i];      // level 4
            float* o5 = ob + 11110 + (size_t)g * 10000 + m3 * 100 + tn * 10;
#pragma unroll
            for (int e = 0; e < 10; e += 2) {
                float2 vv = make_float2(acc[i][e], acc[i][e + 1]);
                *(float2*)&o5[e] = vv;                        // level 5 (8B aligned)
            }
        }
    }
}

extern "C" void kernel_launch(void* const* d_in, const int* in_sizes, int n_in,
                              void* d_out, int out_size, void* d_ws, size_t ws_size,
                              hipStream_t stream) {
    const float* path = (const float*)d_in[0];
    float* out = (float*)d_out;
    int B = in_sizes[0] / (D10 * LPATH);   // 256
    sig_kernel<<<B * G, BLOCK, 0, stream>>>(path, out);
}

// Round 6
// 288.190 us; speedup vs baseline: 5.5256x; 1.0372x over previous
//
#include <hip/hip_runtime.h>

// Path signature depth 5, d=10, L=128, B=256 — vector GEMM formulation (R3
// math, verified) with payload-density + occupancy fixes.
//
// Per (b, g) : level4[m3,c4] = sum_t W1(t)[m3] d_t[c4]
//              level5[m3,c4,e] = sum_t W1(t)[m3] d_t[c4] P(t)[e]
//                              + 1/2 sum_t W0(t)[m3] d_t[c4] d_t[e]
// with P(t)=suffix sum of deltas, W1/W0 Horner chains off scan state S1..S3.
// Block = (b, g-pair): M=200 rows (two g slices). 250 GEMM lanes own 8 rows
// x 10 cols each (acc in regs); 200 scan lanes carry s1,s2,s3 in registers
// (no S1/S2 LDS tables). KC=8 chunk: scan fills W1/W0 panels, GEMM consumes.

#define D10    10
#define LPATH  128
#define NSEG   127
#define BLOCK  256
#define GP     5           // g-pairs per batch
#define KC     8           // segments per chunk
#define RS     12          // dT/Pt row stride (floats, 48B = 16B-aligned)
#define OUT_PER_B 111110

__global__ __launch_bounds__(BLOCK) void sig_kernel(
        const float* __restrict__ path,   // [B][D10][LPATH]
        float* __restrict__ out)          // [B][OUT_PER_B]
{
    __shared__ __align__(16) float dT[NSEG * RS];   // segment increments
    __shared__ __align__(16) float Pt[NSEG * RS];   // suffix sums P(t)
    __shared__ __align__(16) float Wp1[KC * 200];   // W1 panel (rows = g'*100+m3)
    __shared__ __align__(16) float Wp0[KC * 200];   // W0 panel

    const int tid = threadIdx.x;
    const int bb  = blockIdx.x;
    const int b   = bb / GP;
    const int gp  = bb - b * GP;
    const int g0  = gp * 2;
    const float* pb = path + (size_t)b * (D10 * LPATH);

    // ---- delta table ----
    for (int idx = tid; idx < NSEG * D10; idx += BLOCK) {
        int t = idx / D10, c = idx - t * D10;
        dT[t * RS + c] = pb[c * LPATH + t + 1] - pb[c * LPATH + t];
    }
    __syncthreads();
    // ---- Pt suffix (10 lanes, serial) ----
    if (tid < D10) {
        float p = 0.f;
        for (int t = NSEG - 1; t >= 0; t--) { Pt[t * RS + tid] = p; p += dT[t * RS + tid]; }
    }

    // scan-lane identity (tid < 200): row = g'*100 + m3
    const int sg  = (tid >= 100) ? 1 : 0;
    const int m3s = tid - sg * 100;            // 0..99 (valid when tid<200)
    const int gsc = g0 + sg;                   // this lane's c1 channel
    const int c2  = m3s / 10;
    const int c3  = m3s - c2 * 10;
    // GEMM-lane identity (tid < 250): rows tg*8..tg*8+7, col-group c4 = tn
    const int tg  = tid / 10;
    const int tn  = tid - tg * 10;

    float s1 = 0.f, s2 = 0.f, s3 = 0.f;        // scan state (levels 1-3)
    float acc[8][10];
    float s4a[8];
#pragma unroll
    for (int r = 0; r < 8; r++) {
        s4a[r] = 0.f;
#pragma unroll
        for (int e = 0; e < 10; e++) acc[r][e] = 0.f;
    }

    for (int kc0 = 0; kc0 < NSEG; kc0 += KC) {
        const int kn = (NSEG - kc0 < KC) ? (NSEG - kc0) : KC;
        __syncthreads();   // previous GEMM done with Wp (also covers Pt build)

        if (tid < 200) {
            for (int kl = 0; kl < kn; kl++) {
                const int t = kc0 + kl;
                float dg  = dT[t * RS + gsc];
                float dc2 = dT[t * RS + c2];
                float dc3 = dT[t * RS + c3];
                float u24 = s2 + (s1 + dg * 0.25f)       * dc2 * (1.f / 3.f);
                float u25 = s2 + (s1 + dg * 0.2f)        * dc2 * 0.25f;
                float u23 = s2 + (s1 + dg * (1.f / 3.f)) * dc2 * 0.5f;
                Wp1[kl * 200 + tid] = s3 + u24 * dc3 * 0.5f;
                Wp0[kl * 200 + tid] = s3 + u25 * dc3 * (1.f / 3.f);
                s3 += u23 * dc3;
                s2 += (s1 + dg * 0.5f) * dc2;
                s1 += dg;
            }
        }
        __syncthreads();

        if (tid < 250) {
            for (int kl = 0; kl < kn; kl++) {
                const int t = kc0 + kl;
                const float* dr = &dT[t * RS];
                const float* pr = &Pt[t * RS];
                float dn = dr[tn];
                float4 pA = *(const float4*)pr;
                float4 pB = *(const float4*)(pr + 4);
                float2 pC = *(const float2*)(pr + 8);
                float4 dA = *(const float4*)dr;
                float4 dB = *(const float4*)(dr + 4);
                float2 dC = *(const float2*)(dr + 8);
                float pv[10] = {pA.x, pA.y, pA.z, pA.w, pB.x, pB.y, pB.z, pB.w, pC.x, pC.y};
                float dv[10] = {dA.x, dA.y, dA.z, dA.w, dB.x, dB.y, dB.z, dB.w, dC.x, dC.y};
                const int abase = kl * 200 + tg * 8;
                float4 a1a = *(const float4*)&Wp1[abase];
                float4 a1b = *(const float4*)&Wp1[abase + 4];
                float4 a0a = *(const float4*)&Wp0[abase];
                float4 a0b = *(const float4*)&Wp0[abase + 4];
                float A1[8] = {a1a.x, a1a.y, a1a.z, a1a.w, a1b.x, a1b.y, a1b.z, a1b.w};
                float A0[8] = {a0a.x, a0a.y, a0a.z, a0a.w, a0b.x, a0b.y, a0b.z, a0b.w};
                float hdn = dn * 0.5f;
#pragma unroll
                for (int r = 0; r < 8; r++) {
                    float x1 = A1[r] * dn;
                    float x0 = A0[r] * hdn;
                    s4a[r] += x1;
#pragma unroll
                    for (int e = 0; e < 10; e++) {
                        acc[r][e] += x1 * pv[e];
                        acc[r][e] += x0 * dv[e];
                    }
                }
            }
        }
    }

    // ---- epilogue (register state only; no barrier needed) ----
    float* ob = out + (size_t)b * OUT_PER_B;
    if (tid < 200) {
        ob[110 + gsc * 100 + m3s] = s3;                 // level 3
        if (c3 == 0) ob[10 + gsc * 10 + c2] = s2;       // level 2
        if (m3s == 0) ob[gsc] = s1;                     // level 1
    }
    if (tid < 250) {
#pragma unroll
        for (int r = 0; r < 8; r++) {
            int rg = tg * 8 + r;                        // 0..199
            int rsg = (rg >= 100) ? 1 : 0;
            int m3 = rg - rsg * 100;
            int gg = g0 + rsg;
            ob[1110 + gg * 1000 + m3 * 10 + tn] = s4a[r];          // level 4
            float* o5 = ob + 11110 + (size_t)gg * 10000 + m3 * 100 + tn * 10;
#pragma unroll
            for (int e = 0; e < 10; e += 2) {
                float2 vv = make_float2(acc[r][e], acc[r][e + 1]);
                *(float2*)&o5[e] = vv;                             // level 5
            }
        }
    }
}

extern "C" void kernel_launch(void* const* d_in, const int* in_sizes, int n_in,
                              void* d_out, int out_size, void* d_ws, size_t ws_size,
                              hipStream_t stream) {
    const float* path = (const float*)d_in[0];
    float* out = (float*)d_out;
    int B = in_sizes[0] / (D10 * LPATH);   // 256
    sig_kernel<<<B * GP, BLOCK, 0, stream>>>(path, out);
}

// Round 7
// 229.934 us; speedup vs baseline: 6.9256x; 1.2534x over previous
//
#include <hip/hip_runtime.h>

// Path signature depth 5, d=10, L=128, B=256 — Abel-summed vector GEMM.
//
// Verified recurrences (R2/R6): per segment u, with register scan state
// s1,s2,s3 per m3-lane producing W1(u)[m3], W0(u)[m3]:
//   C4(u)[m3,c4] = S4(u)[m3,c4] + 0.5*W0(u)[m3]*d_u[c4]
//   S4(u+1)      = S4(u) + W1(u)[m3]*d_u[c4]
//   level5[m3,c4,e] += C4(u)[m3,c4] * d_u[e]          (K=127, not 254)
//   level4 = S4(NSEG) (free, in registers)
// Block = (b,g), 2560 blocks x 256 threads. Thread owns rows j = tid+250r
// (r<4) of the 1000 (m3,c4) pairs -> c4 = tid%10 uniform per thread; S4 in
// 4 regs; acc 4x10 regs. Scan lanes tid<100 fill W1/W0 LDS panels (KC=16)
// chunk-wise; 2 barriers per chunk. LDS ~19KB -> 8 blocks/CU resident.

#define D10    10
#define LPATH  128
#define NSEG   127
#define BLOCK  256
#define KC     16
#define RS     12          // dT row stride (floats, 48B = 16B aligned)
#define OUT_PER_B 111110

__global__ __launch_bounds__(BLOCK) void sig_kernel(
        const float* __restrict__ path,   // [B][D10][LPATH]
        float* __restrict__ out)          // [B][OUT_PER_B]
{
    __shared__ __align__(16) float dT[NSEG * RS];   // segment increments
    __shared__ float Wp1[KC * 100];                 // W1 panel (chunk)
    __shared__ float Wp0[KC * 100];                 // W0 panel (chunk)

    const int tid = threadIdx.x;
    const int bb  = blockIdx.x;
    const int b   = bb / 10;
    const int g   = bb - b * 10;
    const float* pb = path + (size_t)b * (D10 * LPATH);

    // ---- delta table ----
    for (int idx = tid; idx < NSEG * D10; idx += BLOCK) {
        int t = idx / D10, c = idx - t * D10;
        dT[t * RS + c] = pb[c * LPATH + t + 1] - pb[c * LPATH + t];
    }

    // scan identity (tid<100): m3 = tid, c2 = tid/10, c3 = tid%10
    const int c2 = tid / 10;
    const int c3 = tid - c2 * 10;        // also c4 for GEMM lanes (tid<250)
    int m3r[4];
#pragma unroll
    for (int r = 0; r < 4; r++) m3r[r] = (tid + 250 * r) / 10;

    float s1 = 0.f, s2 = 0.f, s3 = 0.f;  // levels 1-3 scan state (tid<100)
    float S4r[4] = {0.f, 0.f, 0.f, 0.f}; // level-4 prefix rows (tid<250)
    float acc[4][10];
#pragma unroll
    for (int r = 0; r < 4; r++)
#pragma unroll
        for (int e = 0; e < 10; e++) acc[r][e] = 0.f;

    for (int kc0 = 0; kc0 < NSEG; kc0 += KC) {
        const int kn = (NSEG - kc0 < KC) ? (NSEG - kc0) : KC;
        __syncthreads();   // prev chunk's GEMM done with Wp (и dT ready, ch 0)

        if (tid < 100) {
            for (int kl = 0; kl < kn; kl++) {
                const int t = kc0 + kl;
                float dg  = dT[t * RS + g];
                float dc2 = dT[t * RS + c2];
                float dc3 = dT[t * RS + c3];
                float u24 = s2 + (s1 + dg * 0.25f)       * dc2 * (1.f / 3.f);
                float u25 = s2 + (s1 + dg * 0.2f)        * dc2 * 0.25f;
                float u23 = s2 + (s1 + dg * (1.f / 3.f)) * dc2 * 0.5f;
                Wp1[kl * 100 + tid] = s3 + u24 * dc3 * 0.5f;
                Wp0[kl * 100 + tid] = s3 + u25 * dc3 * (1.f / 3.f);
                s3 += u23 * dc3;
                s2 += (s1 + dg * 0.5f) * dc2;
                s1 += dg;
            }
        }
        __syncthreads();

        if (tid < 250) {
            for (int kl = 0; kl < kn; kl++) {
                const int t = kc0 + kl;
                const float* dr = &dT[t * RS];
                float4 dA = *(const float4*)dr;
                float4 dB = *(const float4*)(dr + 4);
                float2 dC = *(const float2*)(dr + 8);
                float de[10] = {dA.x, dA.y, dA.z, dA.w,
                                dB.x, dB.y, dB.z, dB.w, dC.x, dC.y};
                float dc4v = dr[c3];          // c4 = tid%10, LDS b32 broadcast
                float hd   = 0.5f * dc4v;
#pragma unroll
                for (int r = 0; r < 4; r++) {
                    float w1v = Wp1[kl * 100 + m3r[r]];
                    float w0v = Wp0[kl * 100 + m3r[r]];
                    float c4v = S4r[r] + w0v * hd;
                    S4r[r] += w1v * dc4v;
#pragma unroll
                    for (int e = 0; e < 10; e++) acc[r][e] += c4v * de[e];
                }
            }
        }
    }

    // ---- epilogue (all state in registers; no barrier needed) ----
    float* ob = out + (size_t)b * OUT_PER_B;
    if (tid < 100) {
        ob[110 + g * 100 + tid] = s3;               // level 3 (m3 = tid)
        if (c3 == 0) ob[10 + g * 10 + c2] = s2;     // level 2
        if (tid == 0) ob[g] = s1;                   // level 1
    }
    if (tid < 250) {
#pragma unroll
        for (int r = 0; r < 4; r++) {
            const int j = tid + 250 * r;            // = m3*10 + c4
            ob[1110 + g * 1000 + j] = S4r[r];       // level 4
            float* o5 = ob + 11110 + (size_t)g * 10000 + (size_t)j * 10;
#pragma unroll
            for (int e = 0; e < 10; e += 2) {
                float2 vv = make_float2(acc[r][e], acc[r][e + 1]);
                *(float2*)&o5[e] = vv;              // level 5 (8B aligned)
            }
        }
    }
}

extern "C" void kernel_launch(void* const* d_in, const int* in_sizes, int n_in,
                              void* d_out, int out_size, void* d_ws, size_t ws_size,
                              hipStream_t stream) {
    const float* path = (const float*)d_in[0];
    float* out = (float*)d_out;
    int B = in_sizes[0] / (D10 * LPATH);   // 256
    sig_kernel<<<B * 10, BLOCK, 0, stream>>>(path, out);
}